// Round 1
// 1354.191 us; speedup vs baseline: 2.0143x; 2.0143x over previous
//
#include <hip/hip_runtime.h>

// Conv 3x3 SAME, stride 1, C=16 -> O=16, fp32.
// Input viewed as NHWC via raw reshape of NCHW buffer:
//   x[b,h,w,c] = flat[b*16777216 + (h*1024 + w)*16 + c]
// Weight HWIO: w[kh,kw,c,o] = flat[((kh*3+kw)*16 + c)*16 + o]
// Output NCHW: out[b,o,h,w] = flat[((b*16+o)*1024 + h)*1024 + w]
//
// V2 changes vs V1 (2220 us, VALUBusy 15%, WRITE_SIZE 8.8x output):
//  - Kill register spills: V1 held xr[6][16]+acc[4][16] ~ 180 VGPRs in a
//    128-VGPR allocation -> scratch traffic dominated HBM (4.2 GB phantom
//    writes). Now channel-blocked (CB=4): only float4 xr[6] + acc[4][16]
//    + one weight float4 live -> ~110 VGPRs, zero scratch.
//  - XCD-contiguous swizzle: raw%8 = XCD (round-robin dispatch); give XCD k
//    batch k with rows in order so the h+-1 halo rows hit the same L2.

constexpr int Hs = 1024, Ws = 1024, Cs = 16, Os = 16;

__device__ __forceinline__ float f4c(const float4 v, int cl) {
    // cl is compile-time after full unroll
    return cl == 0 ? v.x : cl == 1 ? v.y : cl == 2 ? v.z : v.w;
}

__global__ __launch_bounds__(256, 2)
void conv3x3_c16o16(const float* __restrict__ x,
                    const float* __restrict__ wgt,
                    float* __restrict__ out)
{
    __shared__ float lw[3 * 3 * Cs * Os];   // 2304 floats = 9 KB
    const int t = threadIdx.x;
    // stage weights: 2304 = 9 * 256 exactly
    #pragma unroll
    for (int i = 0; i < 9; ++i) lw[t + 256 * i] = wgt[t + 256 * i];
    __syncthreads();

    // XCD swizzle: grid = 8192 = 8 batches x 1024 rows. Blocks raw%8==k land
    // on XCD k; map them to batch k, row raw>>3 -> consecutive rows (which
    // share 2 of 3 input rows) are processed close in time on the SAME XCD.
    const int raw = (int)blockIdx.x;
    const int b   = raw & 7;
    const int h   = raw >> 3;
    const int w0  = t << 2;              // 4 pixels per thread, full row per block

    const float* xb = x + (size_t)b * ((size_t)Hs * Ws * Cs);

    float acc[4][16];
    #pragma unroll
    for (int p = 0; p < 4; ++p)
        #pragma unroll
        for (int o = 0; o < 16; ++o) acc[p][o] = 0.f;

    #pragma unroll 1                      // runtime kh loop: keep body small
    for (int kh = 0; kh < 3; ++kh) {
        const int hh = h - 1 + kh;
        if (hh < 0 || hh >= Hs) continue; // block-uniform branch (zero pad)
        const float* xrow = xb + (size_t)hh * ((size_t)Ws * Cs);

        #pragma unroll 1                  // runtime cb loop: ~7 KB body, I$-safe
        for (int cb = 0; cb < 4; ++cb) {
            // 6 input pixels (w0-1 .. w0+4) x 4 channels -> 24 VGPRs.
            // One pixel's 16 channels = 64 B = one cache line, so the four
            // cb passes over the same pixels are L1 hits after the first.
            float4 xr[6];
            #pragma unroll
            for (int j = 0; j < 6; ++j) {
                const int ww = w0 - 1 + j;
                const bool v = (ww >= 0) && (ww < Ws);
                xr[j] = v ? *(const float4*)(xrow + (size_t)ww * Cs + cb * 4)
                          : make_float4(0.f, 0.f, 0.f, 0.f);
            }

            #pragma unroll
            for (int cl = 0; cl < 4; ++cl) {
                const int c = cb * 4 + cl;
                #pragma unroll
                for (int kw = 0; kw < 3; ++kw) {
                    // 16 output-channel weights, broadcast ds_read_b128 x4,
                    // amortized over 4 pixels -> 16 FMA per ds_read_b128.
                    const float* wp = &lw[((kh * 3 + kw) * Cs + c) * Os];
                    #pragma unroll
                    for (int q = 0; q < 4; ++q) {
                        const float4 wq = ((const float4*)wp)[q];
                        #pragma unroll
                        for (int p = 0; p < 4; ++p) {
                            const float xv = f4c(xr[p + kw], cl);
                            acc[p][4 * q + 0] = fmaf(xv, wq.x, acc[p][4 * q + 0]);
                            acc[p][4 * q + 1] = fmaf(xv, wq.y, acc[p][4 * q + 1]);
                            acc[p][4 * q + 2] = fmaf(xv, wq.z, acc[p][4 * q + 2]);
                            acc[p][4 * q + 3] = fmaf(xv, wq.w, acc[p][4 * q + 3]);
                        }
                    }
                }
            }
        }
    }

    // store: NCHW, float4 along w per output plane (coalesced)
    float* ob = out + (((size_t)b * Os) * Hs + (size_t)h) * Ws + w0;
    #pragma unroll
    for (int o = 0; o < 16; ++o) {
        float4 st = make_float4(acc[0][o], acc[1][o], acc[2][o], acc[3][o]);
        *(float4*)(ob + (size_t)o * (Hs * Ws)) = st;
    }
}

extern "C" void kernel_launch(void* const* d_in, const int* in_sizes, int n_in,
                              void* d_out, int out_size, void* d_ws, size_t ws_size,
                              hipStream_t stream)
{
    const float* x   = (const float*)d_in[0];
    const float* wgt = (const float*)d_in[1];
    float* out       = (float*)d_out;

    dim3 grid(8 * Hs);   // one block per (b, h) row
    dim3 block(256);
    conv3x3_c16o16<<<grid, block, 0, stream>>>(x, wgt, out);
}